// Round 1
// baseline (811.229 us; speedup 1.0000x reference)
//
#include <hip/hip_runtime.h>
#include <math.h>

typedef float f32x4 __attribute__((ext_vector_type(4)));
typedef float f32x2 __attribute__((ext_vector_type(2)));

#define OLDV 50257
#define FINV 52257
#define NEWV 53257
#define DIM  2048
#define TTOK 32768
#define NNUMT 4096
#define HID  8192
#define NCHEB 16
#define NUNITS 6
#define NROWS 96            // NCHEB * NUNITS
#define RADIUS 5.5f
#define PI_F 3.14159265358979f

// ws layouts (floats):
// big  (KCH=32): A[96][8192] @0 (786432) | Ppart[32][96][2048] @786432 (6291456) | P @7077888 (196608) -> 7274496 floats
// small(KCH=16): A @0                     | Ppart[16][96][2048] @786432 (3145728) | P @3932160          -> 4128768 floats
// inv[TTOK] (int) reuses the Ppart region AFTER reduce_P has consumed it.
#define WS_A      0
#define WS_PPART  786432
#define WS_P_BIG  7077888
#define WS_P_SML  3932160
#define WS_TOT_BIG 7274496

__device__ __forceinline__ float gelu_exact(float x) {
    return 0.5f * x * (1.0f + erff(x * 0.70710678118654752f));
}

// A[(m*6+u)][k] = gelu(v_m * W1[0][k] + ue[u][0]*W1[1][k] + ue[u][1]*W1[2][k] + b1[k])
__global__ void build_A(const float* __restrict__ W1, const float* __restrict__ b1,
                        const float* __restrict__ uemb, float* __restrict__ A) {
    int idx = blockIdx.x * 256 + threadIdx.x;    // 96*8192 threads
    int k = idx & (HID - 1);
    int r = idx >> 13;
    int m = r / 6, u = r - 6 * m;
    float theta = (2.0f * (float)m + 1.0f) * (PI_F / (2.0f * NCHEB));
    float vm = RADIUS * cosf(theta);
    float e0 = uemb[u * 2 + 0], e1 = uemb[u * 2 + 1];
    float x = vm * W1[k] + e0 * W1[HID + k] + e1 * W1[2 * HID + k] + b1[k];
    A[r * HID + k] = gelu_exact(x);
}

// Ppart[kc][96][2048] = partial of A[96][8192] @ W2[8192][2048] over K-chunk kc.
// Tile: 96 rows x 128 cols, 256 threads, each thread 6 rows x (4+4) cols.
// LDS per kk: 3x ds_read_b64 (A, bank-spread via stride 98) + 2x ds_read_b128 (W, 2-way free)
// = ~44 LDS cycles per 48 FMA (2x better than previous 47/24).
template<int KPC>
__global__ void __launch_bounds__(256) gemm_P(const float* __restrict__ A,
                                              const float* __restrict__ W2,
                                              float* __restrict__ Ppart) {
    __shared__ float As[32][NROWS + 2];   // stride 98: even (b64-aligned), banks (2k+6r)%32 distinct
    __shared__ float Ws[32][128];
    int ct = blockIdx.x;                  // 0..15  -> 128-col tile
    int kc = blockIdx.y;                  // K chunk
    int tid = threadIdx.x;
    int c0 = ct * 128;
    int kbase = kc * KPC;
    int cg = tid & 15, rg = tid >> 4;     // cols cg*4 / 64+cg*4, rows rg*6..+5

    f32x4 zero = {0.f, 0.f, 0.f, 0.f};
    f32x4 acc[6][2];
    #pragma unroll
    for (int i = 0; i < 6; ++i) { acc[i][0] = zero; acc[i][1] = zero; }

    int l8 = tid & 7;        // A staging: 8 threads/row, float4 each
    int rb = tid >> 3;       // 0..31
    int cw = (tid & 31) * 4; // W2 staging: 32 threads cover 128 cols
    int kw0 = tid >> 5;      // 0..7

    for (int kk0 = 0; kk0 < KPC; kk0 += 32) {
        #pragma unroll
        for (int it = 0; it < 3; ++it) {
            int r = it * 32 + rb;
            f32x4 a4 = *(const f32x4*)&A[(size_t)r * HID + kbase + kk0 + l8 * 4];
            As[l8 * 4 + 0][r] = a4.x;
            As[l8 * 4 + 1][r] = a4.y;
            As[l8 * 4 + 2][r] = a4.z;
            As[l8 * 4 + 3][r] = a4.w;
        }
        #pragma unroll
        for (int p = 0; p < 4; ++p) {
            int kw = p * 8 + kw0;
            f32x4 w4 = __builtin_nontemporal_load(
                (const f32x4*)&W2[(size_t)(kbase + kk0 + kw) * DIM + c0 + cw]);
            *(f32x4*)&Ws[kw][cw] = w4;
        }
        __syncthreads();
        #pragma unroll
        for (int kk = 0; kk < 32; ++kk) {
            f32x2 a01 = *(const f32x2*)&As[kk][rg * 6 + 0];
            f32x2 a23 = *(const f32x2*)&As[kk][rg * 6 + 2];
            f32x2 a45 = *(const f32x2*)&As[kk][rg * 6 + 4];
            f32x4 w0 = *(const f32x4*)&Ws[kk][cg * 4];
            f32x4 w1 = *(const f32x4*)&Ws[kk][64 + cg * 4];
            acc[0][0] += a01.x * w0;  acc[0][1] += a01.x * w1;
            acc[1][0] += a01.y * w0;  acc[1][1] += a01.y * w1;
            acc[2][0] += a23.x * w0;  acc[2][1] += a23.x * w1;
            acc[3][0] += a23.y * w0;  acc[3][1] += a23.y * w1;
            acc[4][0] += a45.x * w0;  acc[4][1] += a45.x * w1;
            acc[5][0] += a45.y * w0;  acc[5][1] += a45.y * w1;
        }
        __syncthreads();
    }
    #pragma unroll
    for (int i = 0; i < 6; ++i) {
        int r = rg * 6 + i;
        size_t base = ((size_t)kc * NROWS + r) * DIM + c0;
        *(f32x4*)&Ppart[base + cg * 4]      = acc[i][0];
        *(f32x4*)&Ppart[base + 64 + cg * 4] = acc[i][1];
    }
}

template<int KCH>
__global__ void reduce_P(const float* __restrict__ Ppart, float* __restrict__ P) {
    int idx = blockIdx.x * 256 + threadIdx.x;   // 96*2048 threads
    float s = 0.f;
    #pragma unroll
    for (int c = 0; c < KCH; ++c) s += Ppart[(size_t)c * (NROWS * DIM) + idx];
    P[idx] = s;
}

__global__ void init_inv(int* __restrict__ inv) {
    inv[blockIdx.x * 256 + threadIdx.x] = -1;
}

__global__ void scatter_inv(const int* __restrict__ npos, int* __restrict__ inv) {
    int i = blockIdx.x * 256 + threadIdx.x;     // NNUMT threads
    inv[npos[i]] = i;
}

// One block per token: gather base row; if numeric, fuse the barycentric MLP add.
// out written exactly once, non-temporally (don't evict table/P from L2/L3).
__global__ void __launch_bounds__(256) gather_fused(
        const int* __restrict__ ids, const int* __restrict__ inv,
        const float* __restrict__ vals, const int* __restrict__ units,
        const float* __restrict__ P, const float* __restrict__ b2,
        const f32x4* __restrict__ orig, const f32x4* __restrict__ newe,
        f32x4* __restrict__ out) {
    int t = blockIdx.x;
    int tid = threadIdx.x;
    int id = ids[t];                              // uniform -> scalar load
    const f32x4* src = (id < OLDV) ? orig + (size_t)id * 512
                                   : newe + (size_t)(id - OLDV) * 512;
    f32x4 v0 = src[tid];
    f32x4 v1 = src[tid + 256];

    int ni = inv[t];                              // uniform
    if (ni >= 0) {
        float v = vals[ni];
        v = fminf(fmaxf(v, -RADIUS), RADIUS);
        int u = units[ni];

        float lam[NCHEB];
        float den = 0.f;
        int hit = -1;
        #pragma unroll
        for (int m = 0; m < NCHEB; ++m) {
            float theta = (2.0f * (float)m + 1.0f) * (PI_F / (2.0f * NCHEB));
            float vm = RADIUS * cosf(theta);
            float wm = ((m & 1) ? -1.0f : 1.0f) * sinf(theta);
            float d = v - vm;
            if (fabsf(d) < 1e-6f) hit = m;
            float w = wm / d;
            lam[m] = w;
            den += w;
        }
        if (hit >= 0) {
            #pragma unroll
            for (int m = 0; m < NCHEB; ++m) lam[m] = (m == hit) ? 1.f : 0.f;
        } else {
            float inv_den = 1.0f / den;
            #pragma unroll
            for (int m = 0; m < NCHEB; ++m) lam[m] *= inv_den;
        }

        const f32x4* b2v = (const f32x4*)b2;
        f32x4 s0 = b2v[tid];
        f32x4 s1 = b2v[tid + 256];
        #pragma unroll
        for (int m = 0; m < NCHEB; ++m) {
            const f32x4* Pr = (const f32x4*)&P[(size_t)(m * 6 + u) * DIM];
            s0 += lam[m] * Pr[tid];
            s1 += lam[m] * Pr[tid + 256];
        }
        v0 += s0;
        v1 += s1;
    }
    __builtin_nontemporal_store(v0, &out[(size_t)t * 512 + tid]);
    __builtin_nontemporal_store(v1, &out[(size_t)t * 512 + tid + 256]);
}

extern "C" void kernel_launch(void* const* d_in, const int* in_sizes, int n_in,
                              void* d_out, int out_size, void* d_ws, size_t ws_size,
                              hipStream_t stream) {
    const int*   ids   = (const int*)d_in[0];
    const int*   npos  = (const int*)d_in[1];
    const float* nval  = (const float*)d_in[2];
    const int*   nunit = (const int*)d_in[3];
    const float* orig  = (const float*)d_in[4];
    const float* newe  = (const float*)d_in[5];
    const float* uemb  = (const float*)d_in[6];
    const float* W1    = (const float*)d_in[7];
    const float* b1    = (const float*)d_in[8];
    const float* W2    = (const float*)d_in[9];
    const float* b2    = (const float*)d_in[10];
    float* out = (float*)d_out;
    float* ws  = (float*)d_ws;

    bool big = ws_size >= (size_t)WS_TOT_BIG * sizeof(float);
    float* A     = ws + WS_A;
    float* Ppart = ws + WS_PPART;
    float* P     = big ? (ws + WS_P_BIG) : (ws + WS_P_SML);
    int*   inv   = (int*)Ppart;   // Ppart region is dead after reduce_P

    build_A<<<(NROWS * HID) / 256, 256, 0, stream>>>(W1, b1, uemb, A);
    if (big) {
        gemm_P<256><<<dim3(16, 32), 256, 0, stream>>>(A, W2, Ppart);
        reduce_P<32><<<(NROWS * DIM) / 256, 256, 0, stream>>>(Ppart, P);
    } else {
        gemm_P<512><<<dim3(16, 16), 256, 0, stream>>>(A, W2, Ppart);
        reduce_P<16><<<(NROWS * DIM) / 256, 256, 0, stream>>>(Ppart, P);
    }
    init_inv<<<TTOK / 256, 256, 0, stream>>>(inv);
    scatter_inv<<<NNUMT / 256, 256, 0, stream>>>(npos, inv);
    gather_fused<<<TTOK, 256, 0, stream>>>(ids, inv, nval, nunit, P, b2,
        (const f32x4*)orig, (const f32x4*)newe, (f32x4*)out);
}